// Round 8
// baseline (26933.719 us; speedup 1.0000x reference)
//
#include <hip/hip_runtime.h>

#define NBLK 256
#define NTHR 1024

constexpr int H = 1024, MEL = 80, ATT = 640, TXTD = 640, T = 600, TTXT = 128;
constexpr int G4 = 4096, DIN = H + ATT; // 1664

// ---- workspace layout (floats) ----
constexpr int WS_K     = 0;                  // 128*640
constexpr int WS_V     = WS_K + TTXT * ATT;  // 128*640
constexpr int WS_HBUF  = WS_V + TTXT * ATT;  // 2*1024 (double buffer)
constexpr int WS_H0BUF = WS_HBUF + 2 * H;    // 2*1024
constexpr int WS_H1BUF = WS_H0BUF + 2 * H;   // 2*1024
constexpr int WS_Q     = WS_H1BUF + 2 * H;   // 640
constexpr int WS_CTX   = WS_Q + ATT;         // 640 (unnormalized ctx accum)
constexpr int WS_DEN   = WS_CTX + ATT;       // 1
constexpr int WS_GH    = WS_DEN + 1;         // 1
constexpr int WS_DEC   = (WS_GH + 1 + 15) & ~15;        // 160 (conv accum)
constexpr int WS_A0    = (WS_DEC + 2 * MEL + 15) & ~15; // 1024
constexpr int WS_END   = WS_A0 + H;
constexpr int WS_BAR   = (WS_END + 63) & ~63;  // barrier area (u32s)
// barrier: 16 leaf counters 128B apart, root at +512 u32, epoch at +544 u32

// ---- dynamic LDS layout (floats) ----
constexpr int SM_W0  = 0;                    // 16*1664 Wih0 rows (grow-mapped)
constexpr int SM_H   = SM_W0 + 16 * DIN;     // 1024
constexpr int SM_H0  = SM_H + H;             // 1024
constexpr int SM_H1  = SM_H0 + H;            // 1024
constexpr int SM_ATT = SM_H1 + H;            // 640
constexpr int SM_K   = SM_ATT + ATT;         // 640 (this block's K row)
constexpr int SM_V   = SM_K + ATT;           // 640
constexpr int SM_VW  = SM_V + ATT;           // 640 (v_w)
constexpr int SM_OUT = SM_VW + ATT;          // 80
constexpr int SM_DEC = SM_OUT + MEL;         // 160
constexpr int SM_RED = SM_DEC + 2 * MEL;     // 16
constexpr int SM_D   = SM_RED + 16;          // 4
constexpr int SM_DEN = SM_D + 4;             // 1
constexpr int SM_CNT = SM_DEN + 1;
constexpr size_t SM_BYTES = ((size_t)SM_CNT * 4 + 255) & ~(size_t)255;

// Opaque-ify a float4 so the compiler cannot rematerialize it as a reload:
// the value must stay resident in VGPRs for its whole live range.
#define KEEP4(v) \
  asm volatile("" : "+v"((v).x), "+v"((v).y), "+v"((v).z), "+v"((v).w))

struct Params {
  const float *residual, *text, *Wih_a, *Whh_a, *bih_a, *bhh_a,
      *Wq, *Wk, *Wv, *v_w, *Wih0, *Whh0, *bih0, *bhh0,
      *Wih1, *Whh1, *bih1, *bhh1, *D0w, *D0b, *D1w, *D1b,
      *conv_w, *conv_b, *gate_w, *gate_b;
  float* out;
  float* ws;
};

__device__ __forceinline__ float sigm(float x) { return 1.0f / (1.0f + __expf(-x)); }
__device__ __forceinline__ float ftanh(float x) {
  x = fminf(15.f, fmaxf(-15.f, x));
  float e = __expf(2.f * x);
  return (e - 1.f) / (e + 1.f);
}

// Coherent (agent-scope, cache-bypassing) accessors for mutable ws data.
__device__ __forceinline__ float aload(const float* p) {
  return __hip_atomic_load(p, __ATOMIC_RELAXED, __HIP_MEMORY_SCOPE_AGENT);
}
__device__ __forceinline__ void astore(float* p, float v) {
  __hip_atomic_store(p, v, __ATOMIC_RELAXED, __HIP_MEMORY_SCOPE_AGENT);
}

// Fence-light grid barrier (no L2 wb/inv): drain own vmem, then hierarchical
// relaxed-atomic arrival tree (16 padded leaves -> root -> epoch), poll epoch.
__device__ __forceinline__ void gbar(unsigned* bar, unsigned k) {
  asm volatile("s_waitcnt vmcnt(0)" ::: "memory");
  __syncthreads();
  if (threadIdx.x == 0) {
    unsigned* leaf = bar + (blockIdx.x & 15) * 32;  // 128B apart
    unsigned o = __hip_atomic_fetch_add(leaf, 1u, __ATOMIC_RELAXED,
                                        __HIP_MEMORY_SCOPE_AGENT);
    if ((o & 15) == 15) {  // 16 arrivals per leaf
      unsigned r = __hip_atomic_fetch_add(bar + 512, 1u, __ATOMIC_RELAXED,
                                          __HIP_MEMORY_SCOPE_AGENT);
      if ((r & 15) == 15)
        __hip_atomic_fetch_add(bar + 544, 1u, __ATOMIC_RELAXED,
                               __HIP_MEMORY_SCOPE_AGENT);
    }
    while (__hip_atomic_load(bar + 544, __ATOMIC_RELAXED,
                             __HIP_MEMORY_SCOPE_AGENT) < k)
      __builtin_amdgcn_s_sleep(1);
  }
  __syncthreads();
}

__device__ __forceinline__ float red64(float s) {
#pragma unroll
  for (int off = 32; off; off >>= 1) s += __shfl_xor(s, off, 64);
  return s;
}

// partial dot of 1024-length row held in 4 pinned float4s vs x (LDS)
__device__ __forceinline__ float dot16pin(float4 w0, float4 w1, float4 w2,
                                          float4 w3, const float* x, int lane) {
  const float4* x4 = (const float4*)x;
  float4 b0 = x4[lane], b1 = x4[lane + 64], b2 = x4[lane + 128],
         b3 = x4[lane + 192];
  float s0 = w0.x * b0.x, s1 = w1.x * b1.x;
  s0 = fmaf(w0.y, b0.y, s0); s1 = fmaf(w1.y, b1.y, s1);
  s0 = fmaf(w0.z, b0.z, s0); s1 = fmaf(w1.z, b1.z, s1);
  s0 = fmaf(w0.w, b0.w, s0); s1 = fmaf(w1.w, b1.w, s1);
  s0 = fmaf(w2.x, b2.x, s0); s1 = fmaf(w3.x, b3.x, s1);
  s0 = fmaf(w2.y, b2.y, s0); s1 = fmaf(w3.y, b3.y, s1);
  s0 = fmaf(w2.z, b2.z, s0); s1 = fmaf(w3.z, b3.z, s1);
  s0 = fmaf(w2.w, b2.w, s0); s1 = fmaf(w3.w, b3.w, s1);
  return s0 + s1;
}

// partial dot of 1024-length row (any address space) vs x
__device__ __forceinline__ float dot16load(const float* w, const float* x,
                                           int lane) {
  const float4* w4 = (const float4*)w;
  const float4* x4 = (const float4*)x;
  float4 a0 = w4[lane], a1 = w4[lane + 64], a2 = w4[lane + 128],
         a3 = w4[lane + 192];
  float4 b0 = x4[lane], b1 = x4[lane + 64], b2 = x4[lane + 128],
         b3 = x4[lane + 192];
  float s0 = a0.x * b0.x, s1 = a1.x * b1.x;
  s0 = fmaf(a0.y, b0.y, s0); s1 = fmaf(a1.y, b1.y, s1);
  s0 = fmaf(a0.z, b0.z, s0); s1 = fmaf(a1.z, b1.z, s1);
  s0 = fmaf(a0.w, b0.w, s0); s1 = fmaf(a1.w, b1.w, s1);
  s0 = fmaf(a2.x, b2.x, s0); s1 = fmaf(a3.x, b3.x, s1);
  s0 = fmaf(a2.y, b2.y, s0); s1 = fmaf(a3.y, b3.y, s1);
  s0 = fmaf(a2.z, b2.z, s0); s1 = fmaf(a3.z, b3.z, s1);
  s0 = fmaf(a2.w, b2.w, s0); s1 = fmaf(a3.w, b3.w, s1);
  return s0 + s1;
}

__device__ __forceinline__ float wave_dot(const float* __restrict__ w,
                                          const float* __restrict__ x,
                                          int n4, int lane) {
  float s = 0.f;
  const float4* w4 = (const float4*)w;
  const float4* x4 = (const float4*)x;
  for (int i = lane; i < n4; i += 64) {
    float4 a = w4[i];
    float4 b = x4[i];
    s = fmaf(a.x, b.x, s);
    s = fmaf(a.y, b.y, s);
    s = fmaf(a.z, b.z, s);
    s = fmaf(a.w, b.w, s);
  }
  return red64(s);
}

__global__ void __launch_bounds__(NTHR, 4) ar_kernel(Params p) {
  const int b = blockIdx.x;
  const int tid = threadIdx.x;
  const int wave = tid >> 6;   // 0..15
  const int lane = tid & 63;
  const int sg = wave >> 2;    // element subgroup 0..3
  const int wg = wave & 3;     // gate / k-chunk within subgroup
  const int gw = b * 16 + wave;  // global wave 0..4095

  float* ws = p.ws;
  float* Kw = ws + WS_K;
  float* Vw = ws + WS_V;
  float* hbuf = ws + WS_HBUF;
  float* h0buf = ws + WS_H0BUF;
  float* h1buf = ws + WS_H1BUF;
  float* qv = ws + WS_Q;
  float* ctxa = ws + WS_CTX;
  float* den = ws + WS_DEN;
  float* ghp = ws + WS_GH;
  float* dec = ws + WS_DEC;
  float* a0 = ws + WS_A0;
  unsigned* bar = (unsigned*)(ws + WS_BAR);

  extern __shared__ __align__(16) float smem[];
  float* s_w0 = smem + SM_W0;
  float* s_h = smem + SM_H;
  float* s_h0 = smem + SM_H0;
  float* s_h1 = smem + SM_H1;
  float* s_att = smem + SM_ATT;
  float* s_k = smem + SM_K;
  float* s_v = smem + SM_V;
  float* s_vw = smem + SM_VW;
  float* s_out = smem + SM_OUT;
  float* s_dec = smem + SM_DEC;
  float* s_red = smem + SM_RED;
  float* s_d = smem + SM_D;
  float* s_den = smem + SM_DEN;

  const int e = 4 * b + sg;
  const int grow = e + wg * H;  // row for phases A(gate), B, D, E

  // ---- pin invariant weight rows in registers; KEEP4 makes them opaque so
  // the compiler cannot sink the loads back into the t-loop (round-7 bug:
  // VGPR_Count=64 proved all "pinned" rows were rematerialized每step) ----
  const float4* WA = (const float4*)(p.Whh_a + (size_t)grow * H);
  float4 wa0 = WA[lane], wa1 = WA[lane + 64], wa2 = WA[lane + 128],
         wa3 = WA[lane + 192];
  KEEP4(wa0); KEEP4(wa1); KEEP4(wa2); KEEP4(wa3);
  const float4* W0 = (const float4*)(p.Whh0 + (size_t)grow * H);
  float4 w00 = W0[lane], w01 = W0[lane + 64], w02 = W0[lane + 128],
         w03 = W0[lane + 192];
  KEEP4(w00); KEEP4(w01); KEEP4(w02); KEEP4(w03);
  const float4* W1 = (const float4*)(p.Whh1 + (size_t)grow * H);
  float4 w10 = W1[lane], w11 = W1[lane + 64], w12 = W1[lane + 128],
         w13 = W1[lane + 192];
  KEEP4(w10); KEEP4(w11); KEEP4(w12); KEEP4(w13);
  const float4* WI = (const float4*)(p.Wih1 + (size_t)grow * H);
  float4 wi0 = WI[lane], wi1 = WI[lane + 64], wi2 = WI[lane + 128],
         wi3 = WI[lane + 192];
  KEEP4(wi0); KEEP4(wi1); KEEP4(wi2); KEEP4(wi3);
  float4 wma = make_float4(0.f, 0.f, 0.f, 0.f);
  if (lane < MEL / 4)
    wma = ((const float4*)(p.Wih_a + (size_t)grow * MEL))[lane];
  KEEP4(wma);
  float4 wf = ((const float4*)(p.D0w + (size_t)e * H))[wg * 64 + lane];
  KEEP4(wf);
  float4 wgd = ((const float4*)(p.D1w + (size_t)e * H))[wg * 64 + lane];
  KEEP4(wgd);
  float4 wcv = make_float4(0.f, 0.f, 0.f, 0.f);
  if (tid < 2 * MEL) wcv = ((const float4*)(p.conv_w + (size_t)tid * H))[b];
  KEEP4(wcv);
  const float ba = p.bih_a[grow] + p.bhh_a[grow];
  const float b0s = p.bih0[grow] + p.bhh0[grow];
  const float b1s = p.bih1[grow] + p.bhh1[grow];

  // Wq row / gate_w source for phase B (streamed; IC-resident, 2.6 MB/step)
  const float* xsrc = nullptr;
  if (gw < ATT) xsrc = p.Wq + (size_t)gw * H;
  else if (gw == ATT) xsrc = p.gate_w;

  // ---- stage this block's Wih0 rows (grow-mapped) into LDS ----
  {
    const float4* src = (const float4*)(p.Wih0 + (size_t)grow * DIN);
    float4* dst = (float4*)(s_w0 + wave * DIN);
    for (int i = lane; i < DIN / 4; i += 64) dst[i] = src[i];
  }
  for (int i = tid; i < ATT; i += NTHR) s_vw[i] = p.v_w[i];

  // block-private LSTM cell states (element 4b+tid, threads 0..3 only)
  float c_reg = 0.f, c0_reg = 0.f, c1_reg = 0.f;
  // per-wave scalars carried between phases (same wave produces & consumes)
  float u0_reg = 0.f, u1_reg = 0.f, w0h_reg = 0.f;

  unsigned bk = 0;

  // ---------------- init: zero state, precompute K,V (atomic stores) -------
  if (b == 0) {
    for (int i = tid; i < 6 * H; i += NTHR) astore(&hbuf[i], 0.f);
  }
  for (int idx = gw; idx < 2 * TTXT * ATT; idx += NBLK * 16) {
    int isV = idx >= TTXT * ATT;
    int rem = isV ? idx - TTXT * ATT : idx;
    int j = rem / ATT;
    int a = rem - j * ATT;
    const float* wrow = (isV ? p.Wv : p.Wk) + a * TXTD;
    float s = wave_dot(wrow, p.text + j * TXTD, TXTD / 4, lane);
    if (lane == 0) astore(&(isV ? Vw : Kw)[j * ATT + a], s);
  }
  gbar(bar, ++bk);
  // stage this block's K/V row to LDS (attention blocks only)
  if (b < TTXT) {
    for (int i = tid; i < ATT; i += NTHR) {
      s_k[i] = aload(&Kw[b * ATT + i]);
      s_v[i] = aload(&Vw[b * ATT + i]);
    }
  }

  // ---------------- main sequential loop ----------------
  for (int t = 0; t < T; ++t) {
    const float* h_old = hbuf + (t & 1) * H;
    float* h_new = hbuf + ((t + 1) & 1) * H;
    const float* h0_old = h0buf + (t & 1) * H;
    float* h0_new = h0buf + ((t + 1) & 1) * H;
    const float* h1_old = h1buf + (t & 1) * H;
    float* h1_new = h1buf + ((t + 1) & 1) * H;

    // ---- Phase A: stage prev state; prev output; gates + u0/u1 (pinned) ----
    s_h[tid] = aload(h_old + tid);
    s_h0[tid] = aload(h0_old + tid);
    s_h1[tid] = aload(h1_old + tid);
    if (tid < 2 * MEL) s_dec[tid] = aload(dec + tid);
    __syncthreads();
    if (tid < MEL) {
      float o = 0.f;
      if (t != 0) {
        float ls = s_dec[tid] + p.conv_b[tid];
        float bb = s_dec[MEL + tid] + p.conv_b[MEL + tid];
        float r = p.residual[(T - t) * MEL + tid];
        o = (r - bb) * __expf(-ls);
        if (b == 0) p.out[(T - t) * MEL + tid] = o;
      }
      s_out[tid] = o;
    }
    __syncthreads();
    {
      float pa = dot16pin(wa0, wa1, wa2, wa3, s_h, lane);
      if (lane < MEL / 4) {
        float4 bm = ((const float4*)s_out)[lane];
        pa = fmaf(wma.x, bm.x, pa);
        pa = fmaf(wma.y, bm.y, pa);
        pa = fmaf(wma.z, bm.z, pa);
        pa = fmaf(wma.w, bm.w, pa);
      }
      float pu0 = dot16pin(w00, w01, w02, w03, s_h0, lane);
      float pu1 = dot16pin(w10, w11, w12, w13, s_h1, lane);
      pa = red64(pa);
      u0_reg = red64(pu0);  // kept in-wave for phase D
      u1_reg = red64(pu1);  // kept in-wave for phase E
      if (lane == 0) s_red[wave] = pa + ba;
      __syncthreads();
      if (tid < 4) {
        int ee = 4 * b + tid;
        float gi = s_red[tid * 4 + 0], gf = s_red[tid * 4 + 1];
        float gg = s_red[tid * 4 + 2], go = s_red[tid * 4 + 3];
        float c2 = sigm(gf) * c_reg + sigm(gi) * ftanh(gg);
        c_reg = c2;
        astore(&h_new[ee], sigm(go) * ftanh(c2));
      }
    }
    gbar(bar, ++bk);

    // ---- Phase B: stage h_new; w0h from LDS weights; qv/gate (streamed) ----
    s_h[tid] = aload(h_new + tid);
    __syncthreads();
    {
      float s0 = dot16load(s_w0 + wave * DIN, s_h, lane);
      w0h_reg = red64(s0);  // kept in-wave for phase D
      if (xsrc) {
        float q = dot16load(xsrc, s_h, lane);
        q = red64(q);
        if (lane == 0) {
          if (gw < ATT) astore(&qv[gw], q);
          else astore(&ghp[0], q);
        }
      }
      if (b == NBLK - 1) {
        for (int i = tid; i < ATT; i += NTHR) astore(&ctxa[i], 0.f);
        if (tid == 0) astore(den, 0.f);
        for (int i = tid; i < 2 * MEL; i += NTHR) astore(&dec[i], 0.f);
      }
    }
    gbar(bar, ++bk);

    // ---- Phase C: scores -> exp -> ctx accumulation (fixed-shift softmax) --
    if (b < TTXT) {
      if (tid < ATT) s_att[tid] = aload(&qv[tid]);
      __syncthreads();
      float sp = 0.f;
      for (int i = tid; i < ATT; i += NTHR)
        sp += ftanh(s_att[i] + s_k[i]) * s_vw[i];
      sp = red64(sp);
      if (lane == 0) s_red[wave] = sp;
      __syncthreads();
      float sc = 0.f;
#pragma unroll
      for (int k = 0; k < 16; ++k) sc += s_red[k];
      float pj = __expf(sc - 16.f);  // scores bounded ~±11, shift is safe
      for (int i = tid; i < ATT; i += NTHR)
        atomicAdd(&ctxa[i], pj * s_v[i]);
      if (tid == 0) atomicAdd(den, pj);
    }
    gbar(bar, ++bk);

    // ---- Phase D: dec LSTM0: ctx part from LDS weights (unnorm, *inv) ------
    {
      if (tid < ATT) s_att[tid] = aload(&ctxa[tid]);
      if (tid == NTHR - 1) s_den[0] = aload(den);
      __syncthreads();
      const float4* W4 = (const float4*)(s_w0 + wave * DIN + H);
      const float4* X4 = (const float4*)s_att;
      float4 a_ = W4[lane], b_ = X4[lane];
      float4 a2 = W4[lane + 64], b2 = X4[lane + 64];
      float s = a_.x * b_.x;
      s = fmaf(a_.y, b_.y, s); s = fmaf(a_.z, b_.z, s); s = fmaf(a_.w, b_.w, s);
      s = fmaf(a2.x, b2.x, s); s = fmaf(a2.y, b2.y, s);
      s = fmaf(a2.z, b2.z, s); s = fmaf(a2.w, b2.w, s);
      if (lane < 32) {
        float4 a3 = W4[128 + lane], b3 = X4[128 + lane];
        s = fmaf(a3.x, b3.x, s); s = fmaf(a3.y, b3.y, s);
        s = fmaf(a3.z, b3.z, s); s = fmaf(a3.w, b3.w, s);
      }
      s = red64(s);
      float inv = 1.f / s_den[0];
      if (lane == 0) s_red[wave] = s * inv + w0h_reg + u0_reg + b0s;
      if (b == 0 && wave == 15) {
        float gc = wave_dot(p.gate_w + H, s_att, ATT / 4, lane);
        if (lane == 0) {
          float gh = aload(&ghp[0]);
          p.out[T * MEL + t] = sigm(gh + gc * inv + p.gate_b[0]);
        }
      }
      __syncthreads();
      if (tid < 4) {
        int ee = 4 * b + tid;
        float gi = s_red[tid * 4 + 0], gf = s_red[tid * 4 + 1];
        float gg = s_red[tid * 4 + 2], go = s_red[tid * 4 + 3];
        float c2 = sigm(gf) * c0_reg + sigm(gi) * ftanh(gg);
        c0_reg = c2;
        astore(&h0_new[ee], sigm(go) * ftanh(c2));
      }
    }
    gbar(bar, ++bk);

    // ---- Phase E: dec LSTM1 (pinned Wih1 row) ----
    s_h[tid] = aload(h0_new + tid);
    __syncthreads();
    {
      float pe = dot16pin(wi0, wi1, wi2, wi3, s_h, lane);
      pe = red64(pe);
      if (lane == 0) s_red[wave] = pe + u1_reg + b1s;
      __syncthreads();
      if (tid < 4) {
        int ee = 4 * b + tid;
        float gi = s_red[tid * 4 + 0], gf = s_red[tid * 4 + 1];
        float gg = s_red[tid * 4 + 2], go = s_red[tid * 4 + 3];
        float c2 = sigm(gf) * c1_reg + sigm(gi) * ftanh(gg);
        c1_reg = c2;
        astore(&h1_new[ee], sigm(go) * ftanh(c2));
      }
    }
    gbar(bar, ++bk);

    // ---- Phase F: a0 = tanh(D0w@h1 + D0b); pinned D0w f4, k-split 4 waves --
    s_h[tid] = aload(h1_new + tid);
    __syncthreads();
    {
      float4 x = ((const float4*)s_h)[wg * 64 + lane];
      float s = wf.x * x.x;
      s = fmaf(wf.y, x.y, s); s = fmaf(wf.z, x.z, s); s = fmaf(wf.w, x.w, s);
      s = red64(s);
      if (lane == 0) s_red[wave] = s;
      __syncthreads();
      if (tid < 4) {
        int r2 = 4 * b + tid;
        float tot = s_red[tid * 4] + s_red[tid * 4 + 1] + s_red[tid * 4 + 2] +
                    s_red[tid * 4 + 3];
        astore(&a0[r2], ftanh(tot + p.D0b[r2]));
      }
    }
    gbar(bar, ++bk);

    // ---- Phase G: d = tanh(D1w@a0 + D1b); conv partial into dec ----
    s_h[tid] = aload(a0 + tid);
    __syncthreads();
    {
      float4 x = ((const float4*)s_h)[wg * 64 + lane];
      float s = wgd.x * x.x;
      s = fmaf(wgd.y, x.y, s); s = fmaf(wgd.z, x.z, s); s = fmaf(wgd.w, x.w, s);
      s = red64(s);
      if (lane == 0) s_red[wave] = s;
      __syncthreads();
      if (tid < 4) {
        int r2 = 4 * b + tid;
        float tot = s_red[tid * 4] + s_red[tid * 4 + 1] + s_red[tid * 4 + 2] +
                    s_red[tid * 4 + 3];
        s_d[tid] = ftanh(tot + p.D1b[r2]);
      }
      __syncthreads();
      if (tid < 2 * MEL) {
        float acc = wcv.x * s_d[0];
        acc = fmaf(wcv.y, s_d[1], acc);
        acc = fmaf(wcv.z, s_d[2], acc);
        acc = fmaf(wcv.w, s_d[3], acc);
        atomicAdd(&dec[tid], acc);
      }
    }
    gbar(bar, ++bk);
  }

  // ---- epilogue: output for t = T-1 (total[0]) ----
  if (b == 0 && tid < MEL) {
    float ls = aload(&dec[tid]) + p.conv_b[tid];
    float bb = aload(&dec[MEL + tid]) + p.conv_b[MEL + tid];
    float r = p.residual[tid];
    p.out[tid] = (r - bb) * __expf(-ls);
  }
}

extern "C" void kernel_launch(void* const* d_in, const int* in_sizes, int n_in,
                              void* d_out, int out_size, void* d_ws, size_t ws_size,
                              hipStream_t stream) {
  Params hp;
  hp.residual = (const float*)d_in[0];
  hp.text = (const float*)d_in[1];
  hp.Wih_a = (const float*)d_in[2];
  hp.Whh_a = (const float*)d_in[3];
  hp.bih_a = (const float*)d_in[4];
  hp.bhh_a = (const float*)d_in[5];
  hp.Wq = (const float*)d_in[6];
  hp.Wk = (const float*)d_in[7];
  hp.Wv = (const float*)d_in[8];
  hp.v_w = (const float*)d_in[9];
  hp.Wih0 = (const float*)d_in[10];
  hp.Whh0 = (const float*)d_in[11];
  hp.bih0 = (const float*)d_in[12];
  hp.bhh0 = (const float*)d_in[13];
  hp.Wih1 = (const float*)d_in[14];
  hp.Whh1 = (const float*)d_in[15];
  hp.bih1 = (const float*)d_in[16];
  hp.bhh1 = (const float*)d_in[17];
  hp.D0w = (const float*)d_in[18];
  hp.D0b = (const float*)d_in[19];
  hp.D1w = (const float*)d_in[20];
  hp.D1b = (const float*)d_in[21];
  hp.conv_w = (const float*)d_in[22];
  hp.conv_b = (const float*)d_in[23];
  hp.gate_w = (const float*)d_in[24];
  hp.gate_b = (const float*)d_in[25];
  hp.out = (float*)d_out;
  hp.ws = (float*)d_ws;

  // barrier counters must be 0 before the kernel runs (ws is poisoned 0xAA
  // before every timed launch; memset node is graph-capturable).
  hipMemsetAsync((char*)d_ws + (size_t)WS_BAR * sizeof(float), 0, 4096, stream);

  void* args[] = {&hp};
  hipLaunchCooperativeKernel((void*)ar_kernel, dim3(NBLK), dim3(NTHR), args,
                             (uint32_t)SM_BYTES, stream);
}

// Round 9
// 26198.544 us; speedup vs baseline: 1.0281x; 1.0281x over previous
//
#include <hip/hip_runtime.h>

#define NBLK 256
#define NTHR 1024

constexpr int H = 1024, MEL = 80, ATT = 640, TXTD = 640, T = 600, TTXT = 128;
constexpr int G4 = 4096, DIN = H + ATT; // 1664

// ---- workspace layout (floats) ----
constexpr int WS_K     = 0;                  // 128*640
constexpr int WS_V     = WS_K + TTXT * ATT;  // 128*640
constexpr int WS_HV    = WS_V + TTXT * ATT;  // 1024 h_new
constexpr int WS_H0V   = WS_HV + H;          // 1024 h0_new
constexpr int WS_H1V   = WS_H0V + H;         // 1024 h1_new
constexpr int WS_Q     = WS_H1V + H;         // 640
constexpr int WS_CTX   = WS_Q + ATT;         // 640 (unnormalized ctx accum)
constexpr int WS_DEN   = WS_CTX + ATT;       // 1
constexpr int WS_GH    = WS_DEN + 1;         // 1
constexpr int WS_DEC   = (WS_GH + 1 + 15) & ~15;        // 160 (conv accum)
constexpr int WS_A0    = (WS_DEC + 2 * MEL + 15) & ~15; // 1024
constexpr int WS_END   = WS_A0 + H;
constexpr int WS_BAR   = (WS_END + 63) & ~63;  // barrier area (u32s)
// barrier: 16 leaf counters 128B apart; epoch at +544 u32 (16 bumps/barrier)

// ---- dynamic LDS layout (floats) ----
constexpr int SM_W0  = 0;                    // 16*1664 Wih0 rows (grow-mapped)
constexpr int SM_H   = SM_W0 + 16 * DIN;     // 1024 (persists B(t)->A(t+1))
constexpr int SM_H0  = SM_H + H;             // 1024 (persists E(t)->)
constexpr int SM_H1  = SM_H0 + H;            // 1024 (persists F(t)->)
constexpr int SM_A0  = SM_H1 + H;            // 1024
constexpr int SM_ATT = SM_A0 + H;            // 640
constexpr int SM_K   = SM_ATT + ATT;         // 640 (this block's K row)
constexpr int SM_V   = SM_K + ATT;           // 640
constexpr int SM_VW  = SM_V + ATT;           // 640 (v_w)
constexpr int SM_OUT = SM_VW + ATT;          // 80
constexpr int SM_DEC = SM_OUT + MEL;         // 160
constexpr int SM_RED = SM_DEC + 2 * MEL;     // 16
constexpr int SM_D   = SM_RED + 16;          // 4
constexpr int SM_DEN = SM_D + 4;             // 1
constexpr int SM_CNT = SM_DEN + 1;
constexpr size_t SM_BYTES = ((size_t)SM_CNT * 4 + 255) & ~(size_t)255;

#define KEEP4(v) \
  asm volatile("" : "+v"((v).x), "+v"((v).y), "+v"((v).z), "+v"((v).w))

struct Params {
  const float *residual, *text, *Wih_a, *Whh_a, *bih_a, *bhh_a,
      *Wq, *Wk, *Wv, *v_w, *Wih0, *Whh0, *bih0, *bhh0,
      *Wih1, *Whh1, *bih1, *bhh1, *D0w, *D0b, *D1w, *D1b,
      *conv_w, *conv_b, *gate_w, *gate_b;
  float* out;
  float* ws;
};

__device__ __forceinline__ float sigm(float x) { return 1.0f / (1.0f + __expf(-x)); }
__device__ __forceinline__ float ftanh(float x) {
  x = fminf(15.f, fmaxf(-15.f, x));
  float e = __expf(2.f * x);
  return (e - 1.f) / (e + 1.f);
}

__device__ __forceinline__ float aload(const float* p) {
  return __hip_atomic_load(p, __ATOMIC_RELAXED, __HIP_MEMORY_SCOPE_AGENT);
}
__device__ __forceinline__ void astore(float* p, float v) {
  __hip_atomic_store(p, v, __ATOMIC_RELAXED, __HIP_MEMORY_SCOPE_AGENT);
}

// Split barrier: arrive (drain vmem + leaf->epoch atomic) / wait (poll epoch).
// Deferred LDS-only work can be placed between arrive and wait — it runs
// while other blocks are still arriving, hiding the barrier latency.
__device__ __forceinline__ void g_arrive(unsigned* bar) {
  asm volatile("s_waitcnt vmcnt(0)" ::: "memory");
  __syncthreads();
  if (threadIdx.x == 0) {
    unsigned* leaf = bar + (blockIdx.x & 15) * 32;  // 128B apart
    unsigned o = __hip_atomic_fetch_add(leaf, 1u, __ATOMIC_RELAXED,
                                        __HIP_MEMORY_SCOPE_AGENT);
    if ((o & 15) == 15)  // 16 arrivals per leaf -> bump epoch
      __hip_atomic_fetch_add(bar + 544, 1u, __ATOMIC_RELAXED,
                             __HIP_MEMORY_SCOPE_AGENT);
  }
}
__device__ __forceinline__ void g_wait(unsigned* bar, unsigned target) {
  if (threadIdx.x == 0) {
    while (__hip_atomic_load(bar + 544, __ATOMIC_RELAXED,
                             __HIP_MEMORY_SCOPE_AGENT) < target)
      __builtin_amdgcn_s_sleep(1);
  }
  __syncthreads();
}

__device__ __forceinline__ float red64(float s) {
#pragma unroll
  for (int off = 32; off; off >>= 1) s += __shfl_xor(s, off, 64);
  return s;
}

__device__ __forceinline__ float dot16pin(float4 w0, float4 w1, float4 w2,
                                          float4 w3, const float* x, int lane) {
  const float4* x4 = (const float4*)x;
  float4 b0 = x4[lane], b1 = x4[lane + 64], b2 = x4[lane + 128],
         b3 = x4[lane + 192];
  float s0 = w0.x * b0.x, s1 = w1.x * b1.x;
  s0 = fmaf(w0.y, b0.y, s0); s1 = fmaf(w1.y, b1.y, s1);
  s0 = fmaf(w0.z, b0.z, s0); s1 = fmaf(w1.z, b1.z, s1);
  s0 = fmaf(w0.w, b0.w, s0); s1 = fmaf(w1.w, b1.w, s1);
  s0 = fmaf(w2.x, b2.x, s0); s1 = fmaf(w3.x, b3.x, s1);
  s0 = fmaf(w2.y, b2.y, s0); s1 = fmaf(w3.y, b3.y, s1);
  s0 = fmaf(w2.z, b2.z, s0); s1 = fmaf(w3.z, b3.z, s1);
  s0 = fmaf(w2.w, b2.w, s0); s1 = fmaf(w3.w, b3.w, s1);
  return s0 + s1;
}

__device__ __forceinline__ float dot16load(const float* w, const float* x,
                                           int lane) {
  const float4* w4 = (const float4*)w;
  const float4* x4 = (const float4*)x;
  float4 a0 = w4[lane], a1 = w4[lane + 64], a2 = w4[lane + 128],
         a3 = w4[lane + 192];
  float4 b0 = x4[lane], b1 = x4[lane + 64], b2 = x4[lane + 128],
         b3 = x4[lane + 192];
  float s0 = a0.x * b0.x, s1 = a1.x * b1.x;
  s0 = fmaf(a0.y, b0.y, s0); s1 = fmaf(a1.y, b1.y, s1);
  s0 = fmaf(a0.z, b0.z, s0); s1 = fmaf(a1.z, b1.z, s1);
  s0 = fmaf(a0.w, b0.w, s0); s1 = fmaf(a1.w, b1.w, s1);
  s0 = fmaf(a2.x, b2.x, s0); s1 = fmaf(a3.x, b3.x, s1);
  s0 = fmaf(a2.y, b2.y, s0); s1 = fmaf(a3.y, b3.y, s1);
  s0 = fmaf(a2.z, b2.z, s0); s1 = fmaf(a3.z, b3.z, s1);
  s0 = fmaf(a2.w, b2.w, s0); s1 = fmaf(a3.w, b3.w, s1);
  return s0 + s1;
}

__device__ __forceinline__ float wave_dot(const float* __restrict__ w,
                                          const float* __restrict__ x,
                                          int n4, int lane) {
  float s = 0.f;
  const float4* w4 = (const float4*)w;
  const float4* x4 = (const float4*)x;
  for (int i = lane; i < n4; i += 64) {
    float4 a = w4[i];
    float4 b = x4[i];
    s = fmaf(a.x, b.x, s);
    s = fmaf(a.y, b.y, s);
    s = fmaf(a.z, b.z, s);
    s = fmaf(a.w, b.w, s);
  }
  return red64(s);
}

__global__ void __launch_bounds__(NTHR, 4) ar_kernel(Params p) {
  const int b = blockIdx.x;
  const int tid = threadIdx.x;
  const int wave = tid >> 6;   // 0..15
  const int lane = tid & 63;
  const int sg = wave >> 2;    // element subgroup 0..3
  const int wg = wave & 3;     // gate / k-chunk within subgroup
  const int gw = b * 16 + wave;  // global wave 0..4095

  float* ws = p.ws;
  float* Kw = ws + WS_K;
  float* Vw = ws + WS_V;
  float* hv = ws + WS_HV;
  float* h0v = ws + WS_H0V;
  float* h1v = ws + WS_H1V;
  float* qv = ws + WS_Q;
  float* ctxa = ws + WS_CTX;
  float* den = ws + WS_DEN;
  float* ghp = ws + WS_GH;
  float* dec = ws + WS_DEC;
  float* a0g = ws + WS_A0;
  unsigned* bar = (unsigned*)(ws + WS_BAR);

  extern __shared__ __align__(16) float smem[];
  float* s_w0 = smem + SM_W0;
  float* s_h = smem + SM_H;
  float* s_h0 = smem + SM_H0;
  float* s_h1 = smem + SM_H1;
  float* s_a0 = smem + SM_A0;
  float* s_att = smem + SM_ATT;
  float* s_k = smem + SM_K;
  float* s_v = smem + SM_V;
  float* s_vw = smem + SM_VW;
  float* s_out = smem + SM_OUT;
  float* s_dec = smem + SM_DEC;
  float* s_red = smem + SM_RED;
  float* s_d = smem + SM_D;
  float* s_den = smem + SM_DEN;

  const int e = 4 * b + sg;
  const int grow = e + wg * H;  // row for phases A(gate), B, D, E

  // ---- invariant weight rows (compiler may remat; KEEP4 asks it not to) ----
  const float4* WA = (const float4*)(p.Whh_a + (size_t)grow * H);
  float4 wa0 = WA[lane], wa1 = WA[lane + 64], wa2 = WA[lane + 128],
         wa3 = WA[lane + 192];
  KEEP4(wa0); KEEP4(wa1); KEEP4(wa2); KEEP4(wa3);
  const float4* W0 = (const float4*)(p.Whh0 + (size_t)grow * H);
  float4 w00 = W0[lane], w01 = W0[lane + 64], w02 = W0[lane + 128],
         w03 = W0[lane + 192];
  KEEP4(w00); KEEP4(w01); KEEP4(w02); KEEP4(w03);
  const float4* W1 = (const float4*)(p.Whh1 + (size_t)grow * H);
  float4 w10 = W1[lane], w11 = W1[lane + 64], w12 = W1[lane + 128],
         w13 = W1[lane + 192];
  KEEP4(w10); KEEP4(w11); KEEP4(w12); KEEP4(w13);
  const float4* WI = (const float4*)(p.Wih1 + (size_t)grow * H);
  float4 wi0 = WI[lane], wi1 = WI[lane + 64], wi2 = WI[lane + 128],
         wi3 = WI[lane + 192];
  KEEP4(wi0); KEEP4(wi1); KEEP4(wi2); KEEP4(wi3);
  float4 wma = make_float4(0.f, 0.f, 0.f, 0.f);
  if (lane < MEL / 4)
    wma = ((const float4*)(p.Wih_a + (size_t)grow * MEL))[lane];
  KEEP4(wma);
  float4 wf = ((const float4*)(p.D0w + (size_t)e * H))[wg * 64 + lane];
  KEEP4(wf);
  float4 wgd = ((const float4*)(p.D1w + (size_t)e * H))[wg * 64 + lane];
  KEEP4(wgd);
  float4 wcv = make_float4(0.f, 0.f, 0.f, 0.f);
  if (tid < 2 * MEL) wcv = ((const float4*)(p.conv_w + (size_t)tid * H))[b];
  KEEP4(wcv);
  const float ba = p.bih_a[grow] + p.bhh_a[grow];
  const float b0s = p.bih0[grow] + p.bhh0[grow];
  const float b1s = p.bih1[grow] + p.bhh1[grow];

  // Wq row / gate_w source for phase B (streamed, L2/IC-resident)
  const float* xsrc = nullptr;
  if (gw < ATT) xsrc = p.Wq + (size_t)gw * H;
  else if (gw == ATT) xsrc = p.gate_w;

  // ---- stage this block's Wih0 rows (grow-mapped) into LDS ----
  {
    const float4* src = (const float4*)(p.Wih0 + (size_t)grow * DIN);
    float4* dst = (float4*)(s_w0 + wave * DIN);
    for (int i = lane; i < DIN / 4; i += 64) dst[i] = src[i];
  }
  for (int i = tid; i < ATT; i += NTHR) s_vw[i] = p.v_w[i];
  // zero the persistent state vectors (t=0 reads them as prev state)
  s_h[tid] = 0.f;
  s_h0[tid] = 0.f;
  s_h1[tid] = 0.f;

  // block-private LSTM cell states (element 4b+tid, threads 0..3 only)
  float c_reg = 0.f, c0_reg = 0.f, c1_reg = 0.f;
  // per-wave scalars carried between phases (same wave produces & consumes)
  float u0_reg = 0.f, u1_reg = 0.f, w0h_reg = 0.f;

  unsigned bk = 0;

  // ---------------- init: precompute K,V (atomic stores) -------------------
  for (int idx = gw; idx < 2 * TTXT * ATT; idx += NBLK * 16) {
    int isV = idx >= TTXT * ATT;
    int rem = isV ? idx - TTXT * ATT : idx;
    int j = rem / ATT;
    int a = rem - j * ATT;
    const float* wrow = (isV ? p.Wv : p.Wk) + a * TXTD;
    float s = wave_dot(wrow, p.text + j * TXTD, TXTD / 4, lane);
    if (lane == 0) astore(&(isV ? Vw : Kw)[j * ATT + a], s);
  }
  g_arrive(bar); ++bk; g_wait(bar, 16 * bk);
  if (b < TTXT) {
    for (int i = tid; i < ATT; i += NTHR) {
      s_k[i] = aload(&Kw[b * ATT + i]);
      s_v[i] = aload(&Vw[b * ATT + i]);
    }
  }

  // ---------------- main sequential loop ----------------
  for (int t = 0; t < T; ++t) {
    // ---- Phase A: out from dec; attn-LSTM gates (s_h persisted from B) ----
    if (tid < 2 * MEL) s_dec[tid] = aload(dec + tid);
    __syncthreads();
    if (tid < MEL) {
      float o = 0.f;
      if (t != 0) {
        float ls = s_dec[tid] + p.conv_b[tid];
        float bb = s_dec[MEL + tid] + p.conv_b[MEL + tid];
        float r = p.residual[(T - t) * MEL + tid];
        o = (r - bb) * __expf(-ls);
        if (b == 0) p.out[(T - t) * MEL + tid] = o;
      }
      s_out[tid] = o;
    }
    __syncthreads();
    {
      float pa = dot16pin(wa0, wa1, wa2, wa3, s_h, lane);
      if (lane < MEL / 4) {
        float4 bm = ((const float4*)s_out)[lane];
        pa = fmaf(wma.x, bm.x, pa);
        pa = fmaf(wma.y, bm.y, pa);
        pa = fmaf(wma.z, bm.z, pa);
        pa = fmaf(wma.w, bm.w, pa);
      }
      pa = red64(pa);
      if (lane == 0) s_red[wave] = pa + ba;
      __syncthreads();
      if (tid < 4) {
        int ee = 4 * b + tid;
        float gi = s_red[tid * 4 + 0], gf = s_red[tid * 4 + 1];
        float gg = s_red[tid * 4 + 2], go = s_red[tid * 4 + 3];
        float c2 = sigm(gf) * c_reg + sigm(gi) * ftanh(gg);
        c_reg = c2;
        astore(&hv[ee], sigm(go) * ftanh(c2));
      }
    }
    g_arrive(bar); ++bk;
    g_wait(bar, 16 * bk);

    // ---- Phase B: stage h_new; qv/gate; (w0h deferred under barrier) ------
    s_h[tid] = aload(hv + tid);  // persists into A(t+1)
    __syncthreads();
    if (xsrc) {
      float q = dot16load(xsrc, s_h, lane);
      q = red64(q);
      if (lane == 0) {
        if (gw < ATT) astore(&qv[gw], q);
        else astore(&ghp[0], q);
      }
    }
    if (b == NBLK - 1) {
      for (int i = tid; i < ATT; i += NTHR) astore(&ctxa[i], 0.f);
      if (tid == 0) astore(den, 0.f);
      for (int i = tid; i < 2 * MEL; i += NTHR) astore(&dec[i], 0.f);
    }
    g_arrive(bar); ++bk;
    w0h_reg = red64(dot16load(s_w0 + wave * DIN, s_h, lane));  // deferred
    g_wait(bar, 16 * bk);

    // ---- Phase C: scores -> exp -> ctx accumulation (fixed-shift) ---------
    if (b < TTXT) {
      if (tid < ATT) s_att[tid] = aload(&qv[tid]);
      __syncthreads();
      float sp = 0.f;
      for (int i = tid; i < ATT; i += NTHR)
        sp += ftanh(s_att[i] + s_k[i]) * s_vw[i];
      sp = red64(sp);
      if (lane == 0) s_red[wave] = sp;
      __syncthreads();
      float sc = 0.f;
#pragma unroll
      for (int k = 0; k < 16; ++k) sc += s_red[k];
      float pj = __expf(sc - 16.f);  // scores bounded ~±11, shift is safe
      for (int i = tid; i < ATT; i += NTHR)
        atomicAdd(&ctxa[i], pj * s_v[i]);
      if (tid == 0) atomicAdd(den, pj);
    }
    g_arrive(bar); ++bk;
    g_wait(bar, 16 * bk);

    // ---- Phase D: dec LSTM0 gates (ctx dot + staged w0h/u0) ---------------
    {
      if (tid < ATT) s_att[tid] = aload(&ctxa[tid]);
      if (tid == NTHR - 1) s_den[0] = aload(den);
      __syncthreads();
      const float4* W4 = (const float4*)(s_w0 + wave * DIN + H);
      const float4* X4 = (const float4*)s_att;
      float4 a_ = W4[lane], b_ = X4[lane];
      float4 a2 = W4[lane + 64], b2 = X4[lane + 64];
      float s = a_.x * b_.x;
      s = fmaf(a_.y, b_.y, s); s = fmaf(a_.z, b_.z, s); s = fmaf(a_.w, b_.w, s);
      s = fmaf(a2.x, b2.x, s); s = fmaf(a2.y, b2.y, s);
      s = fmaf(a2.z, b2.z, s); s = fmaf(a2.w, b2.w, s);
      if (lane < 32) {
        float4 a3 = W4[128 + lane], b3 = X4[128 + lane];
        s = fmaf(a3.x, b3.x, s); s = fmaf(a3.y, b3.y, s);
        s = fmaf(a3.z, b3.z, s); s = fmaf(a3.w, b3.w, s);
      }
      s = red64(s);
      float inv = 1.f / s_den[0];
      if (lane == 0) s_red[wave] = s * inv + w0h_reg + u0_reg + b0s;
      __syncthreads();
      if (tid < 4) {
        int ee = 4 * b + tid;
        float gi = s_red[tid * 4 + 0], gf = s_red[tid * 4 + 1];
        float gg = s_red[tid * 4 + 2], go = s_red[tid * 4 + 3];
        float c2 = sigm(gf) * c0_reg + sigm(gi) * ftanh(gg);
        c0_reg = c2;
        astore(&h0v[ee], sigm(go) * ftanh(c2));
      }
    }
    g_arrive(bar); ++bk;
    if (b == 0 && wave == 15) {  // deferred: gate output
      float inv = 1.f / s_den[0];
      float gc = wave_dot(p.gate_w + H, s_att, ATT / 4, lane);
      if (lane == 0) {
        float gh = aload(&ghp[0]);
        p.out[T * MEL + t] = sigm(gh + gc * inv + p.gate_b[0]);
      }
    }
    g_wait(bar, 16 * bk);

    // ---- Phase E: dec LSTM1 gates; (u0' for next step deferred) -----------
    s_h0[tid] = aload(h0v + tid);  // persists (used by deferred u0')
    __syncthreads();
    {
      float pe = dot16pin(wi0, wi1, wi2, wi3, s_h0, lane);
      pe = red64(pe);
      if (lane == 0) s_red[wave] = pe + u1_reg + b1s;
      __syncthreads();
      if (tid < 4) {
        int ee = 4 * b + tid;
        float gi = s_red[tid * 4 + 0], gf = s_red[tid * 4 + 1];
        float gg = s_red[tid * 4 + 2], go = s_red[tid * 4 + 3];
        float c2 = sigm(gf) * c1_reg + sigm(gi) * ftanh(gg);
        c1_reg = c2;
        astore(&h1v[ee], sigm(go) * ftanh(c2));
      }
    }
    g_arrive(bar); ++bk;
    u0_reg = red64(dot16pin(w00, w01, w02, w03, s_h0, lane));  // deferred
    g_wait(bar, 16 * bk);

    // ---- Phase F: a0 = tanh(D0w@h1 + b); (u1' for next step deferred) -----
    s_h1[tid] = aload(h1v + tid);
    __syncthreads();
    {
      float4 x = ((const float4*)s_h1)[wg * 64 + lane];
      float s = wf.x * x.x;
      s = fmaf(wf.y, x.y, s); s = fmaf(wf.z, x.z, s); s = fmaf(wf.w, x.w, s);
      s = red64(s);
      if (lane == 0) s_red[wave] = s;
      __syncthreads();
      if (tid < 4) {
        int r2 = 4 * b + tid;
        float tot = s_red[tid * 4] + s_red[tid * 4 + 1] + s_red[tid * 4 + 2] +
                    s_red[tid * 4 + 3];
        astore(&a0g[r2], ftanh(tot + p.D0b[r2]));
      }
    }
    g_arrive(bar); ++bk;
    u1_reg = red64(dot16pin(w10, w11, w12, w13, s_h1, lane));  // deferred
    g_wait(bar, 16 * bk);

    // ---- Phase G: d = tanh(D1w@a0 + b); conv partial into dec -------------
    s_a0[tid] = aload(a0g + tid);
    __syncthreads();
    {
      float4 x = ((const float4*)s_a0)[wg * 64 + lane];
      float s = wgd.x * x.x;
      s = fmaf(wgd.y, x.y, s); s = fmaf(wgd.z, x.z, s); s = fmaf(wgd.w, x.w, s);
      s = red64(s);
      if (lane == 0) s_red[wave] = s;
      __syncthreads();
      if (tid < 4) {
        int r2 = 4 * b + tid;
        float tot = s_red[tid * 4] + s_red[tid * 4 + 1] + s_red[tid * 4 + 2] +
                    s_red[tid * 4 + 3];
        s_d[tid] = ftanh(tot + p.D1b[r2]);
      }
      __syncthreads();
      if (tid < 2 * MEL) {
        float acc = wcv.x * s_d[0];
        acc = fmaf(wcv.y, s_d[1], acc);
        acc = fmaf(wcv.z, s_d[2], acc);
        acc = fmaf(wcv.w, s_d[3], acc);
        atomicAdd(&dec[tid], acc);
      }
    }
    g_arrive(bar); ++bk;
    g_wait(bar, 16 * bk);
  }

  // ---- epilogue: output for t = T-1 (total[0]) ----
  if (b == 0 && tid < MEL) {
    float ls = aload(&dec[tid]) + p.conv_b[tid];
    float bb = aload(&dec[MEL + tid]) + p.conv_b[MEL + tid];
    float r = p.residual[tid];
    p.out[tid] = (r - bb) * __expf(-ls);
  }
}

extern "C" void kernel_launch(void* const* d_in, const int* in_sizes, int n_in,
                              void* d_out, int out_size, void* d_ws, size_t ws_size,
                              hipStream_t stream) {
  Params hp;
  hp.residual = (const float*)d_in[0];
  hp.text = (const float*)d_in[1];
  hp.Wih_a = (const float*)d_in[2];
  hp.Whh_a = (const float*)d_in[3];
  hp.bih_a = (const float*)d_in[4];
  hp.bhh_a = (const float*)d_in[5];
  hp.Wq = (const float*)d_in[6];
  hp.Wk = (const float*)d_in[7];
  hp.Wv = (const float*)d_in[8];
  hp.v_w = (const float*)d_in[9];
  hp.Wih0 = (const float*)d_in[10];
  hp.Whh0 = (const float*)d_in[11];
  hp.bih0 = (const float*)d_in[12];
  hp.bhh0 = (const float*)d_in[13];
  hp.Wih1 = (const float*)d_in[14];
  hp.Whh1 = (const float*)d_in[15];
  hp.bih1 = (const float*)d_in[16];
  hp.bhh1 = (const float*)d_in[17];
  hp.D0w = (const float*)d_in[18];
  hp.D0b = (const float*)d_in[19];
  hp.D1w = (const float*)d_in[20];
  hp.D1b = (const float*)d_in[21];
  hp.conv_w = (const float*)d_in[22];
  hp.conv_b = (const float*)d_in[23];
  hp.gate_w = (const float*)d_in[24];
  hp.gate_b = (const float*)d_in[25];
  hp.out = (float*)d_out;
  hp.ws = (float*)d_ws;

  hipMemsetAsync((char*)d_ws + (size_t)WS_BAR * sizeof(float), 0, 4096, stream);

  void* args[] = {&hp};
  hipLaunchCooperativeKernel((void*)ar_kernel, dim3(NBLK), dim3(NTHR), args,
                             (uint32_t)SM_BYTES, stream);
}